// Round 11
// baseline (15164.218 us; speedup 1.0000x reference)
//
#include <hip/hip_runtime.h>
#include <cstdint>
#include <cstddef>

#define T_SEQ 4096
#define HSZ   512
#define NGATE 2048   // 4*HSZ
#define DIN   1024
#define NB0   32     // layer-0 blocks per direction
#define HB0   16     // h-elements per layer-0 block
#define NB1   64     // layer-1 blocks per direction
#define HB1   8      // h-elements per layer-1 block
#define S_SLOT 16    // exchange ring slots (power of 2)
#define CH0   68     // skewed LDS chunk stride in floats (64 + 4; 272B = 16B-aligned)

typedef unsigned long long u64;
typedef unsigned int u32;

__device__ __forceinline__ u64 exld(const u64* p) {
  return __hip_atomic_load(p, __ATOMIC_RELAXED, __HIP_MEMORY_SCOPE_AGENT);
}
__device__ __forceinline__ void exst(u64* p, u64 v) {
  __hip_atomic_store(p, v, __ATOMIC_RELAXED, __HIP_MEMORY_SCOPE_AGENT);
}
__device__ __forceinline__ int pgld(const u32* p) {
  return (int)__hip_atomic_load(p, __ATOMIC_RELAXED, __HIP_MEMORY_SCOPE_AGENT);
}
__device__ __forceinline__ void pgst(u32* p, u32 v) {
  __hip_atomic_store(p, v, __ATOMIC_RELAXED, __HIP_MEMORY_SCOPE_AGENT);
}

// wide coherent poll: two 16B system-scope loads (sc0 sc1 bypass L1/L2 -> LLC),
// both in flight before one waitcnt. Semantics validated by R9's passing run.
__device__ __forceinline__ void exld16x2(const u64* p, ulonglong2& A, ulonglong2& B) {
  asm volatile("global_load_dwordx4 %0, %2, off sc0 sc1\n"
               "global_load_dwordx4 %1, %2, off offset:16 sc0 sc1\n"
               "s_waitcnt vmcnt(0)"
               : "=&v"(A), "=&v"(B) : "v"(p) : "memory");
}

// poll 4 consecutive u64 slots until all tags match; wide fast path with sticky
// fallback (after 4096 stale iters) to the proven scalar agent-atomic path.
__device__ __forceinline__ void pollw(const u64* base, u32 tag, bool& fast, float4& out) {
  if (fast) {
    int it = 0;
    for (;;) {
      ulonglong2 A, B;
      exld16x2(base, A, B);
      if ((u32)(A.x >> 32) == tag && (u32)(A.y >> 32) == tag &&
          (u32)(B.x >> 32) == tag && (u32)(B.y >> 32) == tag) {
        out = make_float4(__uint_as_float((u32)A.x), __uint_as_float((u32)A.y),
                          __uint_as_float((u32)B.x), __uint_as_float((u32)B.y));
        return;
      }
      if (++it > 4096) { fast = false; break; }
    }
  }
  u64 v0=0, v1=0, v2=0, v3=0; bool o0=false, o1=false, o2=false, o3=false;
  do {
    if (!o0) { u64 v = exld(base+0); if ((u32)(v>>32) == tag) { v0 = v; o0 = true; } }
    if (!o1) { u64 v = exld(base+1); if ((u32)(v>>32) == tag) { v1 = v; o1 = true; } }
    if (!o2) { u64 v = exld(base+2); if ((u32)(v>>32) == tag) { v2 = v; o2 = true; } }
    if (!o3) { u64 v = exld(base+3); if ((u32)(v>>32) == tag) { v3 = v; o3 = true; } }
  } while (!(o0 && o1 && o2 && o3));
  out = make_float4(__uint_as_float((u32)v0), __uint_as_float((u32)v1),
                    __uint_as_float((u32)v2), __uint_as_float((u32)v3));
}

// fast activations: v_rcp + v_exp (no div sequences, no libm tanh)
__device__ __forceinline__ float frcp(float x) { return __builtin_amdgcn_rcpf(x); }
__device__ __forceinline__ float fsig(float x) { return frcp(1.f + __expf(-x)); }
__device__ __forceinline__ float ftnh(float x) { return 1.f - 2.f * frcp(1.f + __expf(2.f * x)); }

// ---------------- init: zero exchange slots (epoch0 == h_0 == 0) + progress flags ----------------
__global__ void init_sync_kernel(u64* ex, u32* prog) {
  const int tid = blockIdx.x * blockDim.x + threadIdx.x;
  if (tid < 2 * 2 * S_SLOT * HSZ) exst(&ex[tid], 0ull);
  if (tid < 2 * (NB0 + NB1)) pgst(&prog[tid], 0u);
}

// ---------------- fp32 GEMM with bias: P[t,r] = sum_k X[t,k]*W[r,k] + bi[r] + bh[r] ----------------
__global__ __launch_bounds__(256, 2)
void gemm_bias_kernel(const float* __restrict__ Xf, const float* __restrict__ Xb,
                      const float* __restrict__ Wf, const float* __restrict__ Wb,
                      const float* __restrict__ bif, const float* __restrict__ bhf,
                      const float* __restrict__ bib, const float* __restrict__ bhb,
                      float* __restrict__ Pf, float* __restrict__ Pb, int K)
{
  const int dir = blockIdx.z;
  const float* X  = dir ? Xb  : Xf;
  const float* W  = dir ? Wb  : Wf;
  const float* bi = dir ? bib : bif;
  const float* bh = dir ? bhb : bhf;
  float* P        = dir ? Pb  : Pf;

  const int m0 = blockIdx.x * 128;
  const int n0 = blockIdx.y * 128;
  const int tid = threadIdx.x;
  const int lr = tid >> 1;
  const int lk = (tid & 1) * 8;

  __shared__ float As[16*128];
  __shared__ float Bs[16*128];

  float acc[8][8];
  #pragma unroll
  for (int i = 0; i < 8; ++i)
    #pragma unroll
    for (int j = 0; j < 8; ++j) acc[i][j] = 0.f;

  for (int k0 = 0; k0 < K; k0 += 16) {
    const float4 a0 = *(const float4*)(X + (size_t)(m0+lr)*K + k0 + lk);
    const float4 a1 = *(const float4*)(X + (size_t)(m0+lr)*K + k0 + lk + 4);
    const float4 b0 = *(const float4*)(W + (size_t)(n0+lr)*K + k0 + lk);
    const float4 b1 = *(const float4*)(W + (size_t)(n0+lr)*K + k0 + lk + 4);
    __syncthreads();
    As[(lk+0)*128+lr]=a0.x; As[(lk+1)*128+lr]=a0.y; As[(lk+2)*128+lr]=a0.z; As[(lk+3)*128+lr]=a0.w;
    As[(lk+4)*128+lr]=a1.x; As[(lk+5)*128+lr]=a1.y; As[(lk+6)*128+lr]=a1.z; As[(lk+7)*128+lr]=a1.w;
    Bs[(lk+0)*128+lr]=b0.x; Bs[(lk+1)*128+lr]=b0.y; Bs[(lk+2)*128+lr]=b0.z; Bs[(lk+3)*128+lr]=b0.w;
    Bs[(lk+4)*128+lr]=b1.x; Bs[(lk+5)*128+lr]=b1.y; Bs[(lk+6)*128+lr]=b1.z; Bs[(lk+7)*128+lr]=b1.w;
    __syncthreads();
    #pragma unroll
    for (int kk = 0; kk < 16; ++kk) {
      const float4 A0 = *(const float4*)(As + kk*128 + (tid&15)*8);
      const float4 A1 = *(const float4*)(As + kk*128 + (tid&15)*8 + 4);
      const float4 B0 = *(const float4*)(Bs + kk*128 + (tid>>4)*8);
      const float4 B1 = *(const float4*)(Bs + kk*128 + (tid>>4)*8 + 4);
      const float av[8] = {A0.x,A0.y,A0.z,A0.w,A1.x,A1.y,A1.z,A1.w};
      const float bv[8] = {B0.x,B0.y,B0.z,B0.w,B1.x,B1.y,B1.z,B1.w};
      #pragma unroll
      for (int i = 0; i < 8; ++i)
        #pragma unroll
        for (int j = 0; j < 8; ++j) acc[i][j] += av[i]*bv[j];
    }
  }
  const int tm = m0 + (tid&15)*8;
  const int tn = n0 + (tid>>4)*8;
  #pragma unroll
  for (int i = 0; i < 8; ++i) {
    #pragma unroll
    for (int j = 0; j < 8; ++j) {
      const int n = tn + j;
      P[(size_t)(tm+i)*NGATE + n] = acc[i][j] + bi[n] + bh[n];
    }
  }
}

// ---------------- fused persistent recurrence: both layers, both directions, pipelined ----------------
// blocks [0,64): L0 (fwd 0..31, bwd 32..63)   [64,192): L1 (fwd 64..127, bwd 128..191)
// Exchange: u64 = (epoch<<32)|float_bits into slot epoch&(S_SLOT-1), agent scope (LLC).
// R4: 16-slot ring + lazy guard.  R5: in-wave gates, 1 barrier/step.  R10: 2x blocks, 64-col lanes.
// R11: (a) amdgpu_waves_per_eu(2,2): only 1 block/CU can be resident (192 blocks / 256 CUs),
// so pin the allocator at the achievable 2 waves/SIMD -> full 256-reg budget (R10's VGPR=60
// shows it was targeting impossible occupancy and reloading weights from L2 every step);
// (b) weight loads issued at TOP of each iteration, before the poll -> L2 latency hides
// under the poll spin; (c) consolidated wide polls: 128 pollers x 4 slots via 2x16B sc0sc1
// loads (R9-validated) -> 4x fewer LLC poll requests; guards/progress on idle lanes >=256.
__global__ __launch_bounds__(512, 2) __attribute__((amdgpu_waves_per_eu(2, 2)))
void fused_recur_kernel(const float* __restrict__ Whh0_f, const float* __restrict__ Whh0_b,
                        const float* __restrict__ Wih1_f, const float* __restrict__ Whh1_f,
                        const float* __restrict__ bih1_f, const float* __restrict__ bhh1_f,
                        const float* __restrict__ Wih1_b, const float* __restrict__ Whh1_b,
                        const float* __restrict__ bih1_b, const float* __restrict__ bhh1_b,
                        const float* __restrict__ P_f, const float* __restrict__ P_b,
                        u64* ex0, u64* ex1, u32* prog0, u32* prog1,
                        float* __restrict__ out)
{
  const int bx  = blockIdx.x;
  const int tid = threadIdx.x;
  const int lane = tid & 63;
  const int wv   = tid >> 6;

  __shared__ __align__(16) float xh[2][16*CH0];   // double-buffered skewed 64-float chunks

  if (bx < 2*NB0) {
    // ---------------- layer 0 ----------------
    const int dir = (bx >= NB0) ? 1 : 0;
    const int b   = bx - dir*NB0;
    const float* Whh = dir ? Whh0_b : Whh0_f;
    const float* P   = dir ? P_b    : P_f;
    u64* exS   = ex0 + (size_t)dir*S_SLOT*HSZ;   // self exchange (also read by layer 1)
    u32* prS   = prog0 + dir*NB0;
    u32* prL1  = prog1 + dir*NB1;

    // lane = cc*8 + el*4 + g : 8 col-chunks of 64; 4 gates of an element adjacent
    const int g  = lane & 3;
    const int el = (lane >> 2) & 1;
    const int cc = lane >> 3;            // 0..7
    const int e  = wv*2 + el;            // 0..15 per block
    const int grow = g*HSZ + b*HB0 + e;  // global gate-row
    const bool red0 = (cc == 0);
    const bool pub  = red0 && (g == 0);
    const float4* wp = (const float4*)(Whh + (size_t)grow*HSZ + cc*64);

    float creg = 0.f;
    float pv = 0.f;
    if (red0) pv = P[(size_t)(dir ? (T_SEQ-1) : 0)*NGATE + grow];
    bool fastH = true;

    for (int t = 0; t < T_SEQ; ++t) {
      // guards on idle lanes, every 8 steps (consumers: L0 peers + L1 blocks of this dir)
      if ((t & 7) == 0) {
        if (tid >= 256 && tid < 256+NB0)      { while (pgld(&prS[tid-256])  < t-4) {} }
        else if (tid >= 320 && tid < 320+NB1) { while (pgld(&prL1[tid-320]) < t-4) {} }
      }
      // weight loads issued BEFORE the poll: L2 latency hides under the spin
      float4 wr[16];
      #pragma unroll
      for (int j = 0; j < 16; ++j) wr[j] = wp[j];
      // consolidated h-poll: 128 pollers x 4 slots (wide), others go to barrier
      if (tid < 128) {
        const int s = 4*tid;
        float4 hv;
        pollw(exS + (size_t)(t & (S_SLOT-1))*HSZ + s, (u32)t, fastH, hv);
        *(float4*)&xh[t & 1][(s>>6)*CH0 + (s&63)] = hv;
      }
      __syncthreads();
      if (tid == 256) pgst(&prS[b], (u32)(t+1));   // epoch-t reads complete
      // next-step P prefetch (one step of miss-hiding)
      float pvn = 0.f;
      if (red0 && t+1 < T_SEQ) pvn = P[(size_t)(dir ? (T_SEQ-2-t) : (t+1))*NGATE + grow];
      // matvec: 16 float4 from chunk cc (8 chunks x stride-68 floats: conflict-free)
      const float4* h4 = (const float4*)(xh[t & 1] + cc*CH0);
      float a0=0.f, a1=0.f, a2=0.f, a3=0.f;
      #pragma unroll
      for (int j = 0; j < 16; j += 4) {
        const float4 h0 = h4[j], h1 = h4[j+1], h2 = h4[j+2], h3 = h4[j+3];
        a0 += wr[j].x*h0.x   + wr[j].y*h0.y   + wr[j].z*h0.z   + wr[j].w*h0.w;
        a1 += wr[j+1].x*h1.x + wr[j+1].y*h1.y + wr[j+1].z*h1.z + wr[j+1].w*h1.w;
        a2 += wr[j+2].x*h2.x + wr[j+2].y*h2.y + wr[j+2].z*h2.z + wr[j+2].w*h2.w;
        a3 += wr[j+3].x*h3.x + wr[j+3].y*h3.y + wr[j+3].z*h3.z + wr[j+3].w*h3.w;
      }
      float acc = (a0+a1)+(a2+a3);
      acc += __shfl_xor(acc, 8);           // reduce over cc (lane bits 3,4,5)
      acc += __shfl_xor(acc, 16);
      acc += __shfl_xor(acc, 32);
      const float val = acc + pv;          // full row value on cc==0 lanes
      pv = pvn;
      // parallel activation on the 4 gate lanes, then gather
      const float av = (g == 2) ? ftnh(val) : fsig(val);
      const float f1 = __shfl_xor(av, 1);
      const float f2 = __shfl_xor(av, 2);
      const float f3 = __shfl_xor(av, 3);
      if (pub) {
        // lane g=0: av=sig(i); f1=sig(f); f2=tanh(g); f3=sig(o)
        creg = f1*creg + av*f2;
        const float hnew = f3*ftnh(creg);
        const int hidx = b*HB0 + e;
        const u64 pkt = ((u64)(u32)(t+1) << 32) | (u64)__float_as_uint(hnew);
        exst(exS + (size_t)((t+1) & (S_SLOT-1))*HSZ + hidx, pkt);
        if (t == T_SEQ-1) {
          out[dir*HSZ + hidx]        = creg;   // cell_memories layer 0
          out[2048 + dir*HSZ + hidx] = hnew;   // hidden_states layer 0
        }
      }
    }
  } else {
    // ---------------- layer 1 ----------------
    const int r   = bx - 2*NB0;
    const int dir = (r >= NB1) ? 1 : 0;
    const int b   = r - dir*NB1;
    const float* Wih = dir ? Wih1_b : Wih1_f;
    const float* Whh = dir ? Whh1_b : Whh1_f;
    const float* bi  = dir ? bih1_b : bih1_f;
    const float* bh  = dir ? bhh1_b : bhh1_f;
    u64* exX = ex0 + (size_t)dir*S_SLOT*HSZ;     // x source = layer-0 outputs
    u64* exS = ex1 + (size_t)dir*S_SLOT*HSZ;     // self h exchange
    u32* prS = prog1 + dir*NB1;

    // lane = cc*4 + g : 16 col-chunks of 64 (0-7: Wih/x, 8-15: Whh/h); wave = element
    const int g  = lane & 3;
    const int cc = lane >> 2;            // 0..15
    const int e  = wv;                   // 0..7 per block
    const int grow = g*HSZ + b*HB1 + e;
    const bool red0 = (cc == 0);
    const bool pub  = red0 && (g == 0);
    const float4* wp = (const float4*)((cc < 8) ? (Wih + (size_t)grow*HSZ + cc*64)
                                                : (Whh + (size_t)grow*HSZ + (cc-8)*64));

    float brow = 0.f;
    if (red0) brow = bi[grow] + bh[grow];

    float creg = 0.f;
    bool fastX = true, fastH = true;

    for (int t = 0; t < T_SEQ; ++t) {
      // guard on idle lanes, every 8 steps (consumers of ex1: L1 peers of this dir)
      if ((t & 7) == 0 && tid >= 256 && tid < 256+NB1) { while (pgld(&prS[tid-256]) < t-4) {} }
      // weight loads before the poll
      float4 wr[16];
      #pragma unroll
      for (int j = 0; j < 16; ++j) wr[j] = wp[j];
      // consolidated polls: tid<128 -> x (epoch t+1), tid 128..255 -> own h (epoch t)
      if (tid < 128) {
        const int s = 4*tid;
        float4 xv;
        pollw(exX + (size_t)((t+1) & (S_SLOT-1))*HSZ + s, (u32)(t+1), fastX, xv);
        *(float4*)&xh[t & 1][(s>>6)*CH0 + (s&63)] = xv;            // chunks 0..7 (x)
      } else if (tid < 256) {
        const int s = 4*(tid-128);
        float4 hv;
        pollw(exS + (size_t)(t & (S_SLOT-1))*HSZ + s, (u32)t, fastH, hv);
        *(float4*)&xh[t & 1][(8 + (s>>6))*CH0 + (s&63)] = hv;      // chunks 8..15 (h)
      }
      __syncthreads();
      if (tid == 256) pgst(&prS[b], (u32)(t+1));
      // matvec: 16 float4 from chunk cc
      const float4* v4 = (const float4*)(xh[t & 1] + cc*CH0);
      float a0=0.f, a1=0.f, a2=0.f, a3=0.f;
      #pragma unroll
      for (int j = 0; j < 16; j += 4) {
        const float4 h0 = v4[j], h1 = v4[j+1], h2 = v4[j+2], h3 = v4[j+3];
        a0 += wr[j].x*h0.x   + wr[j].y*h0.y   + wr[j].z*h0.z   + wr[j].w*h0.w;
        a1 += wr[j+1].x*h1.x + wr[j+1].y*h1.y + wr[j+1].z*h1.z + wr[j+1].w*h1.w;
        a2 += wr[j+2].x*h2.x + wr[j+2].y*h2.y + wr[j+2].z*h2.z + wr[j+2].w*h2.w;
        a3 += wr[j+3].x*h3.x + wr[j+3].y*h3.y + wr[j+3].z*h3.z + wr[j+3].w*h3.w;
      }
      float acc = (a0+a1)+(a2+a3);
      acc += __shfl_xor(acc, 4);           // reduce over cc (lane bits 2,3,4,5)
      acc += __shfl_xor(acc, 8);
      acc += __shfl_xor(acc, 16);
      acc += __shfl_xor(acc, 32);
      const float val = acc + brow;
      const float av = (g == 2) ? ftnh(val) : fsig(val);
      const float f1 = __shfl_xor(av, 1);
      const float f2 = __shfl_xor(av, 2);
      const float f3 = __shfl_xor(av, 3);
      if (pub) {
        creg = f1*creg + av*f2;
        const float hnew = f3*ftnh(creg);
        const int hidx = b*HB1 + e;
        const u64 pkt = ((u64)(u32)(t+1) << 32) | (u64)__float_as_uint(hnew);
        exst(exS + (size_t)((t+1) & (S_SLOT-1))*HSZ + hidx, pkt);
        const int trow = dir ? (T_SEQ-1-t) : t;
        out[4096 + (size_t)trow*1024 + dir*HSZ + hidx] = hnew;   // top-layer outputs
        if (t == T_SEQ-1) {
          out[1024 + dir*HSZ + hidx]        = creg;   // cell_memories layer 1
          out[2048 + 1024 + dir*HSZ + hidx] = hnew;   // hidden_states layer 1
        }
      }
    }
  }
}

// ---------------- launch ----------------
extern "C" void kernel_launch(void* const* d_in, const int* in_sizes, int n_in,
                              void* d_out, int out_size, void* d_ws, size_t ws_size,
                              hipStream_t stream)
{
  const float* emb   = (const float*)d_in[0];
  const float* fWih0 = (const float*)d_in[1];
  const float* fWhh0 = (const float*)d_in[2];
  const float* fbih0 = (const float*)d_in[3];
  const float* fbhh0 = (const float*)d_in[4];
  const float* fWih1 = (const float*)d_in[5];
  const float* fWhh1 = (const float*)d_in[6];
  const float* fbih1 = (const float*)d_in[7];
  const float* fbhh1 = (const float*)d_in[8];
  const float* bWih0 = (const float*)d_in[9];
  const float* bWhh0 = (const float*)d_in[10];
  const float* bbih0 = (const float*)d_in[11];
  const float* bbhh0 = (const float*)d_in[12];
  const float* bWih1 = (const float*)d_in[13];
  const float* bWhh1 = (const float*)d_in[14];
  const float* bbih1 = (const float*)d_in[15];
  const float* bbhh1 = (const float*)d_in[16];
  float* out = (float*)d_out;

  // workspace: P[2][4096][2048] fp32 (67 MB), ex0/ex1 [2][S_SLOT][512] u64 each, progress flags
  float* P_f = (float*)d_ws;
  float* P_b = P_f + (size_t)T_SEQ*NGATE;
  u64*   ex0 = (u64*)(P_b + (size_t)T_SEQ*NGATE);
  u64*   ex1 = ex0 + 2*S_SLOT*HSZ;
  u32*   prog0 = (u32*)(ex1 + 2*S_SLOT*HSZ);
  u32*   prog1 = prog0 + 2*NB0;

  init_sync_kernel<<<32, 1024, 0, stream>>>(ex0, prog0);

  // layer-0 input projections for both directions (bwd reads P reversed in time)
  gemm_bias_kernel<<<dim3(32,16,2), 256, 0, stream>>>(
      emb, emb, fWih0, bWih0, fbih0, fbhh0, bbih0, bbhh0, P_f, P_b, DIN);

  // fused pipelined recurrence: L0 fwd/bwd + L1 fwd/bwd in one persistent launch
  fused_recur_kernel<<<2*NB0 + 2*NB1, 512, 0, stream>>>(
      fWhh0, bWhh0,
      fWih1, fWhh1, fbih1, fbhh1,
      bWih1, bWhh1, bbih1, bbhh1,
      P_f, P_b, ex0, ex1, prog0, prog1, out);
}

// Round 12
// 12349.398 us; speedup vs baseline: 1.2279x; 1.2279x over previous
//
#include <hip/hip_runtime.h>
#include <cstdint>
#include <cstddef>

#define T_SEQ 4096
#define HSZ   512
#define NGATE 2048   // 4*HSZ
#define DIN   1024
#define NB0   32     // layer-0 blocks per direction
#define HB0   16     // h-elements per layer-0 block
#define NB1   64     // layer-1 blocks per direction
#define HB1   8      // h-elements per layer-1 block
#define S_SLOT 16    // exchange ring slots (power of 2)
#define CH0   68     // skewed LDS chunk stride in floats (64 + 4; 272B = 16B-aligned)
#define WLDS  34816  // weight LDS floats: L0 64 rows x (8*68); L1 32 rows x (16*68) — same size

typedef unsigned long long u64;
typedef unsigned int u32;

__device__ __forceinline__ u64 exld(const u64* p) {
  return __hip_atomic_load(p, __ATOMIC_RELAXED, __HIP_MEMORY_SCOPE_AGENT);
}
__device__ __forceinline__ void exst(u64* p, u64 v) {
  __hip_atomic_store(p, v, __ATOMIC_RELAXED, __HIP_MEMORY_SCOPE_AGENT);
}
__device__ __forceinline__ int pgld(const u32* p) {
  return (int)__hip_atomic_load(p, __ATOMIC_RELAXED, __HIP_MEMORY_SCOPE_AGENT);
}
__device__ __forceinline__ void pgst(u32* p, u32 v) {
  __hip_atomic_store(p, v, __ATOMIC_RELAXED, __HIP_MEMORY_SCOPE_AGENT);
}

// fast activations: v_rcp + v_exp (no div sequences, no libm tanh)
__device__ __forceinline__ float frcp(float x) { return __builtin_amdgcn_rcpf(x); }
__device__ __forceinline__ float fsig(float x) { return frcp(1.f + __expf(-x)); }
__device__ __forceinline__ float ftnh(float x) { return 1.f - 2.f * frcp(1.f + __expf(2.f * x)); }

// ---------------- init: zero exchange slots (epoch0 == h_0 == 0) + progress flags ----------------
__global__ void init_sync_kernel(u64* ex, u32* prog) {
  const int tid = blockIdx.x * blockDim.x + threadIdx.x;
  if (tid < 2 * 2 * S_SLOT * HSZ) exst(&ex[tid], 0ull);
  if (tid < 2 * (NB0 + NB1)) pgst(&prog[tid], 0u);
}

// ---------------- fp32 GEMM with bias: P[t,r] = sum_k X[t,k]*W[r,k] + bi[r] + bh[r] ----------------
__global__ __launch_bounds__(256, 2)
void gemm_bias_kernel(const float* __restrict__ Xf, const float* __restrict__ Xb,
                      const float* __restrict__ Wf, const float* __restrict__ Wb,
                      const float* __restrict__ bif, const float* __restrict__ bhf,
                      const float* __restrict__ bib, const float* __restrict__ bhb,
                      float* __restrict__ Pf, float* __restrict__ Pb, int K)
{
  const int dir = blockIdx.z;
  const float* X  = dir ? Xb  : Xf;
  const float* W  = dir ? Wb  : Wf;
  const float* bi = dir ? bib : bif;
  const float* bh = dir ? bhb : bhf;
  float* P        = dir ? Pb  : Pf;

  const int m0 = blockIdx.x * 128;
  const int n0 = blockIdx.y * 128;
  const int tid = threadIdx.x;
  const int lr = tid >> 1;
  const int lk = (tid & 1) * 8;

  __shared__ float As[16*128];
  __shared__ float Bs[16*128];

  float acc[8][8];
  #pragma unroll
  for (int i = 0; i < 8; ++i)
    #pragma unroll
    for (int j = 0; j < 8; ++j) acc[i][j] = 0.f;

  for (int k0 = 0; k0 < K; k0 += 16) {
    const float4 a0 = *(const float4*)(X + (size_t)(m0+lr)*K + k0 + lk);
    const float4 a1 = *(const float4*)(X + (size_t)(m0+lr)*K + k0 + lk + 4);
    const float4 b0 = *(const float4*)(W + (size_t)(n0+lr)*K + k0 + lk);
    const float4 b1 = *(const float4*)(W + (size_t)(n0+lr)*K + k0 + lk + 4);
    __syncthreads();
    As[(lk+0)*128+lr]=a0.x; As[(lk+1)*128+lr]=a0.y; As[(lk+2)*128+lr]=a0.z; As[(lk+3)*128+lr]=a0.w;
    As[(lk+4)*128+lr]=a1.x; As[(lk+5)*128+lr]=a1.y; As[(lk+6)*128+lr]=a1.z; As[(lk+7)*128+lr]=a1.w;
    Bs[(lk+0)*128+lr]=b0.x; Bs[(lk+1)*128+lr]=b0.y; Bs[(lk+2)*128+lr]=b0.z; Bs[(lk+3)*128+lr]=b0.w;
    Bs[(lk+4)*128+lr]=b1.x; Bs[(lk+5)*128+lr]=b1.y; Bs[(lk+6)*128+lr]=b1.z; Bs[(lk+7)*128+lr]=b1.w;
    __syncthreads();
    #pragma unroll
    for (int kk = 0; kk < 16; ++kk) {
      const float4 A0 = *(const float4*)(As + kk*128 + (tid&15)*8);
      const float4 A1 = *(const float4*)(As + kk*128 + (tid&15)*8 + 4);
      const float4 B0 = *(const float4*)(Bs + kk*128 + (tid>>4)*8);
      const float4 B1 = *(const float4*)(Bs + kk*128 + (tid>>4)*8 + 4);
      const float av[8] = {A0.x,A0.y,A0.z,A0.w,A1.x,A1.y,A1.z,A1.w};
      const float bv[8] = {B0.x,B0.y,B0.z,B0.w,B1.x,B1.y,B1.z,B1.w};
      #pragma unroll
      for (int i = 0; i < 8; ++i)
        #pragma unroll
        for (int j = 0; j < 8; ++j) acc[i][j] += av[i]*bv[j];
    }
  }
  const int tm = m0 + (tid&15)*8;
  const int tn = n0 + (tid>>4)*8;
  #pragma unroll
  for (int i = 0; i < 8; ++i) {
    #pragma unroll
    for (int j = 0; j < 8; ++j) {
      const int n = tn + j;
      P[(size_t)(tm+i)*NGATE + n] = acc[i][j] + bi[n] + bh[n];
    }
  }
}

// ---------------- fused persistent recurrence: both layers, both directions, pipelined ----------------
// blocks [0,64): L0 (fwd 0..31, bwd 32..63)   [64,192): L1 (fwd 64..127, bwd 128..191)
// Exchange: u64 = (epoch<<32)|float_bits into slot epoch&(S_SLOT-1), agent scope (LLC).
// R4: 16-slot ring + lazy guard.  R5: in-wave gates, 1 barrier/step.  R10: 2x blocks, 64-col lanes.
// R12: per-block weight tile (128KB) staged ONCE into LDS at entry; matvec reads weights via
// ds_read_b128. Registers (R5/R9/R11) failed 3x: allocator won't keep a 64-reg array resident.
// LDS removes the per-step weight re-fetch from L2/HBM (FETCH 351MB vs 158MB true traffic)
// and its ~900cy HBM-miss jitter from the serial chain. Layout [row][cc][68]: row stride
// (8 or 16)*68 floats == 0 mod 32 banks, cc*68 == cc*4 banks -> 8 lanes/bank-group (optimal).
__global__ __launch_bounds__(512, 2)
void fused_recur_kernel(const float* __restrict__ Whh0_f, const float* __restrict__ Whh0_b,
                        const float* __restrict__ Wih1_f, const float* __restrict__ Whh1_f,
                        const float* __restrict__ bih1_f, const float* __restrict__ bhh1_f,
                        const float* __restrict__ Wih1_b, const float* __restrict__ Whh1_b,
                        const float* __restrict__ bih1_b, const float* __restrict__ bhh1_b,
                        const float* __restrict__ P_f, const float* __restrict__ P_b,
                        u64* ex0, u64* ex1, u32* prog0, u32* prog1,
                        float* __restrict__ out)
{
  const int bx  = blockIdx.x;
  const int tid = threadIdx.x;
  const int lane = tid & 63;
  const int wv   = tid >> 6;

  __shared__ __align__(16) float wlds[WLDS];        // per-block weight tile (136 KB)
  __shared__ __align__(16) float xh[2][16*CH0];     // double-buffered skewed 64-float chunks

  if (bx < 2*NB0) {
    // ---------------- layer 0 ----------------
    const int dir = (bx >= NB0) ? 1 : 0;
    const int b   = bx - dir*NB0;
    const float* Whh = dir ? Whh0_b : Whh0_f;
    const float* P   = dir ? P_b    : P_f;
    u64* exS   = ex0 + (size_t)dir*S_SLOT*HSZ;   // self exchange (also read by layer 1)
    u32* prS   = prog0 + dir*NB0;
    u32* prL1  = prog1 + dir*NB1;

    // lane = cc*8 + el*4 + g : 8 col-chunks of 64; 4 gates of an element adjacent
    const int g  = lane & 3;
    const int el = (lane >> 2) & 1;
    const int cc = lane >> 3;            // 0..7
    const int e  = wv*2 + el;            // 0..15 per block
    const int grow = g*HSZ + b*HB0 + e;  // global gate-row
    const int rl = e*4 + g;              // local weight row 0..63
    const bool red0 = (cc == 0);
    const bool pub  = red0 && (g == 0);

    // stage weights: 64 rows x 512 cols -> wlds[row*544 + cc*68 + c]
    for (int pass = 0; pass < 16; ++pass) {
      const int idx = pass*512 + tid;        // 0..8191 float4s
      const int r   = idx >> 7;              // 0..63
      const int c4  = idx & 127;             // float4 within row
      const int gg = r & 3, ee = r >> 2;
      const float4 v = *(const float4*)(Whh + (size_t)(gg*HSZ + b*HB0 + ee)*HSZ + c4*4);
      *(float4*)&wlds[r*544 + (c4>>4)*68 + (c4&15)*4] = v;
    }
    __syncthreads();
    const float4* wl = (const float4*)(wlds + rl*544 + cc*68);

    float creg = 0.f;
    float pv = 0.f;
    if (red0) pv = P[(size_t)(dir ? (T_SEQ-1) : 0)*NGATE + grow];

    for (int t = 0; t < T_SEQ; ++t) {
      // slot-overwrite guard, every 8 steps (consumers: L0 peers + L1 blocks of this dir)
      if ((t & 7) == 0) {
        if (tid >= 64 && tid < 64+NB0)        { while (pgld(&prS[tid-64])  < t-4) {} }
        else if (tid >= 96 && tid < 96+NB1)   { while (pgld(&prL1[tid-96]) < t-4) {} }
      }
      // poll h_t (epoch t), stage to skewed LDS: chunk tid>>6, offset tid&63
      {
        const u64* sp = exS + (size_t)(t & (S_SLOT-1))*HSZ + tid;
        u64 v;
        do { v = exld(sp); } while ((u32)(v >> 32) != (u32)t);
        xh[t & 1][(tid>>6)*CH0 + (tid & 63)] = __uint_as_float((u32)v);
      }
      __syncthreads();
      if (tid == 0) pgst(&prS[b], (u32)(t+1));   // epoch-t reads complete
      // next-step P prefetch (one step of miss-hiding)
      float pvn = 0.f;
      if (red0 && t+1 < T_SEQ) pvn = P[(size_t)(dir ? (T_SEQ-2-t) : (t+1))*NGATE + grow];
      // matvec: 16 float4 weights (LDS) x 16 float4 h (LDS)
      const float4* h4 = (const float4*)(xh[t & 1] + cc*CH0);
      float a0=0.f, a1=0.f, a2=0.f, a3=0.f;
      #pragma unroll
      for (int j = 0; j < 16; j += 4) {
        const float4 w0 = wl[j], w1 = wl[j+1], w2 = wl[j+2], w3 = wl[j+3];
        const float4 h0 = h4[j], h1 = h4[j+1], h2 = h4[j+2], h3 = h4[j+3];
        a0 += w0.x*h0.x + w0.y*h0.y + w0.z*h0.z + w0.w*h0.w;
        a1 += w1.x*h1.x + w1.y*h1.y + w1.z*h1.z + w1.w*h1.w;
        a2 += w2.x*h2.x + w2.y*h2.y + w2.z*h2.z + w2.w*h2.w;
        a3 += w3.x*h3.x + w3.y*h3.y + w3.z*h3.z + w3.w*h3.w;
      }
      float acc = (a0+a1)+(a2+a3);
      acc += __shfl_xor(acc, 8);           // reduce over cc (lane bits 3,4,5)
      acc += __shfl_xor(acc, 16);
      acc += __shfl_xor(acc, 32);
      const float val = acc + pv;          // full row value on cc==0 lanes
      pv = pvn;
      // parallel activation on the 4 gate lanes, then gather
      const float av = (g == 2) ? ftnh(val) : fsig(val);
      const float f1 = __shfl_xor(av, 1);
      const float f2 = __shfl_xor(av, 2);
      const float f3 = __shfl_xor(av, 3);
      if (pub) {
        // lane g=0: av=sig(i); f1=sig(f); f2=tanh(g); f3=sig(o)
        creg = f1*creg + av*f2;
        const float hnew = f3*ftnh(creg);
        const int hidx = b*HB0 + e;
        const u64 pkt = ((u64)(u32)(t+1) << 32) | (u64)__float_as_uint(hnew);
        exst(exS + (size_t)((t+1) & (S_SLOT-1))*HSZ + hidx, pkt);
        if (t == T_SEQ-1) {
          out[dir*HSZ + hidx]        = creg;   // cell_memories layer 0
          out[2048 + dir*HSZ + hidx] = hnew;   // hidden_states layer 0
        }
      }
    }
  } else {
    // ---------------- layer 1 ----------------
    const int r   = bx - 2*NB0;
    const int dir = (r >= NB1) ? 1 : 0;
    const int b   = r - dir*NB1;
    const float* Wih = dir ? Wih1_b : Wih1_f;
    const float* Whh = dir ? Whh1_b : Whh1_f;
    const float* bi  = dir ? bih1_b : bih1_f;
    const float* bh  = dir ? bhh1_b : bhh1_f;
    u64* exX = ex0 + (size_t)dir*S_SLOT*HSZ;     // x source = layer-0 outputs
    u64* exS = ex1 + (size_t)dir*S_SLOT*HSZ;     // self h exchange
    u32* prS = prog1 + dir*NB1;

    // lane = cc*4 + g : 16 col-chunks of 64 (0-7: Wih/x, 8-15: Whh/h); wave = element
    const int g  = lane & 3;
    const int cc = lane >> 2;            // 0..15
    const int e  = wv;                   // 0..7 per block
    const int grow = g*HSZ + b*HB1 + e;
    const int rl = e*4 + g;              // local weight row 0..31
    const bool red0 = (cc == 0);
    const bool pub  = red0 && (g == 0);

    // stage weights: 32 rows x 1024 cols (x-half then h-half) -> wlds[row*1088 + cc*68 + c]
    for (int pass = 0; pass < 16; ++pass) {
      const int idx = pass*512 + tid;        // 0..8191 float4s
      const int r2  = idx >> 8;              // 0..31
      const int c4  = idx & 255;             // float4 within 1024-col row
      const int gg = r2 & 3, ee = r2 >> 2;
      const int col = c4*4;
      const float* src = (col < 512) ? (Wih + (size_t)(gg*HSZ + b*HB1 + ee)*HSZ + col)
                                     : (Whh + (size_t)(gg*HSZ + b*HB1 + ee)*HSZ + (col-512));
      *(float4*)&wlds[r2*1088 + (c4>>4)*68 + (c4&15)*4] = *(const float4*)src;
    }
    __syncthreads();
    const float4* wl = (const float4*)(wlds + rl*1088 + cc*68);

    float brow = 0.f;
    if (red0) brow = bi[grow] + bh[grow];

    float creg = 0.f;
    u64 xpf = exld(exX + (size_t)(1 & (S_SLOT-1))*HSZ + tid);   // prefetch x epoch 1

    for (int t = 0; t < T_SEQ; ++t) {
      // slot-overwrite guard, every 8 steps (consumers of ex1: L1 peers of this dir)
      if ((t & 7) == 0 && tid >= 64 && tid < 64+NB1) { while (pgld(&prS[tid-64]) < t-4) {} }
      // poll x_t (epoch t+1; usually satisfied by prefetch) and own h_t (epoch t)
      {
        const u64* px = exX + (size_t)((t+1) & (S_SLOT-1))*HSZ + tid;
        const u64* ph = exS + (size_t)(t & (S_SLOT-1))*HSZ + tid;
        u64 vx = xpf; bool okx = ((u32)(vx >> 32) == (u32)(t+1));
        float hv = 0.f; bool okh = false;
        do {
          if (!okx) { u64 v = exld(px); if ((u32)(v >> 32) == (u32)(t+1)) { vx = v; okx = true; } }
          if (!okh) { u64 v = exld(ph); if ((u32)(v >> 32) == (u32)t)     { hv = __uint_as_float((u32)v); okh = true; } }
        } while (!(okx && okh));
        xh[t & 1][(tid>>6)*CH0 + (tid & 63)]       = __uint_as_float((u32)vx);   // chunks 0..7 (x)
        xh[t & 1][(8 + (tid>>6))*CH0 + (tid & 63)] = hv;                         // chunks 8..15 (h)
      }
      __syncthreads();
      if (tid == 0) pgst(&prS[b], (u32)(t+1));
      xpf = exld(exX + (size_t)((t+2) & (S_SLOT-1))*HSZ + tid);   // prefetch next x (epoch-tagged)
      // matvec: 16 float4 weights (LDS) x 16 float4 x|h (LDS)
      const float4* v4 = (const float4*)(xh[t & 1] + cc*CH0);
      float a0=0.f, a1=0.f, a2=0.f, a3=0.f;
      #pragma unroll
      for (int j = 0; j < 16; j += 4) {
        const float4 w0 = wl[j], w1 = wl[j+1], w2 = wl[j+2], w3 = wl[j+3];
        const float4 h0 = v4[j], h1 = v4[j+1], h2 = v4[j+2], h3 = v4[j+3];
        a0 += w0.x*h0.x + w0.y*h0.y + w0.z*h0.z + w0.w*h0.w;
        a1 += w1.x*h1.x + w1.y*h1.y + w1.z*h1.z + w1.w*h1.w;
        a2 += w2.x*h2.x + w2.y*h2.y + w2.z*h2.z + w2.w*h2.w;
        a3 += w3.x*h3.x + w3.y*h3.y + w3.z*h3.z + w3.w*h3.w;
      }
      float acc = (a0+a1)+(a2+a3);
      acc += __shfl_xor(acc, 4);           // reduce over cc (lane bits 2,3,4,5)
      acc += __shfl_xor(acc, 8);
      acc += __shfl_xor(acc, 16);
      acc += __shfl_xor(acc, 32);
      const float val = acc + brow;
      const float av = (g == 2) ? ftnh(val) : fsig(val);
      const float f1 = __shfl_xor(av, 1);
      const float f2 = __shfl_xor(av, 2);
      const float f3 = __shfl_xor(av, 3);
      if (pub) {
        creg = f1*creg + av*f2;
        const float hnew = f3*ftnh(creg);
        const int hidx = b*HB1 + e;
        const u64 pkt = ((u64)(u32)(t+1) << 32) | (u64)__float_as_uint(hnew);
        exst(exS + (size_t)((t+1) & (S_SLOT-1))*HSZ + hidx, pkt);
        const int trow = dir ? (T_SEQ-1-t) : t;
        out[4096 + (size_t)trow*1024 + dir*HSZ + hidx] = hnew;   // top-layer outputs
        if (t == T_SEQ-1) {
          out[1024 + dir*HSZ + hidx]        = creg;   // cell_memories layer 1
          out[2048 + 1024 + dir*HSZ + hidx] = hnew;   // hidden_states layer 1
        }
      }
    }
  }
}

// ---------------- launch ----------------
extern "C" void kernel_launch(void* const* d_in, const int* in_sizes, int n_in,
                              void* d_out, int out_size, void* d_ws, size_t ws_size,
                              hipStream_t stream)
{
  const float* emb   = (const float*)d_in[0];
  const float* fWih0 = (const float*)d_in[1];
  const float* fWhh0 = (const float*)d_in[2];
  const float* fbih0 = (const float*)d_in[3];
  const float* fbhh0 = (const float*)d_in[4];
  const float* fWih1 = (const float*)d_in[5];
  const float* fWhh1 = (const float*)d_in[6];
  const float* fbih1 = (const float*)d_in[7];
  const float* fbhh1 = (const float*)d_in[8];
  const float* bWih0 = (const float*)d_in[9];
  const float* bWhh0 = (const float*)d_in[10];
  const float* bbih0 = (const float*)d_in[11];
  const float* bbhh0 = (const float*)d_in[12];
  const float* bWih1 = (const float*)d_in[13];
  const float* bWhh1 = (const float*)d_in[14];
  const float* bbih1 = (const float*)d_in[15];
  const float* bbhh1 = (const float*)d_in[16];
  float* out = (float*)d_out;

  // workspace: P[2][4096][2048] fp32 (67 MB), ex0/ex1 [2][S_SLOT][512] u64 each, progress flags
  float* P_f = (float*)d_ws;
  float* P_b = P_f + (size_t)T_SEQ*NGATE;
  u64*   ex0 = (u64*)(P_b + (size_t)T_SEQ*NGATE);
  u64*   ex1 = ex0 + 2*S_SLOT*HSZ;
  u32*   prog0 = (u32*)(ex1 + 2*S_SLOT*HSZ);
  u32*   prog1 = prog0 + 2*NB0;

  init_sync_kernel<<<32, 1024, 0, stream>>>(ex0, prog0);

  // layer-0 input projections for both directions (bwd reads P reversed in time)
  gemm_bias_kernel<<<dim3(32,16,2), 256, 0, stream>>>(
      emb, emb, fWih0, bWih0, fbih0, fbhh0, bbih0, bbhh0, P_f, P_b, DIN);

  // fused pipelined recurrence: L0 fwd/bwd + L1 fwd/bwd in one persistent launch
  fused_recur_kernel<<<2*NB0 + 2*NB1, 512, 0, stream>>>(
      fWhh0, bWhh0,
      fWih1, fWhh1, fbih1, fbhh1,
      bWih1, bWhh1, bbih1, bbhh1,
      P_f, P_b, ex0, ex1, prog0, prog1, out);
}

// Round 13
// 6787.660 us; speedup vs baseline: 2.2341x; 1.8194x over previous
//
#include <hip/hip_runtime.h>
#include <cstdint>
#include <cstddef>

#define T_SEQ 4096
#define HSZ   512
#define NGATE 2048   // 4*HSZ
#define DIN   1024
#define NB0   32     // layer-0 blocks per direction
#define HB0   16     // h-elements per layer-0 block
#define NB1   64     // layer-1 blocks per direction
#define HB1   8      // h-elements per layer-1 block
#define S_SLOT 16    // exchange ring slots (power of 2)
#define CH0   68     // skewed LDS chunk stride in floats (64 + 4; 272B = 16B-aligned)

typedef unsigned long long u64;
typedef unsigned int u32;

__device__ __forceinline__ u64 exld(const u64* p) {
  return __hip_atomic_load(p, __ATOMIC_RELAXED, __HIP_MEMORY_SCOPE_AGENT);
}
// publish via atomic exchange: agent-scope RMW executes AT the LLC and allocates the
// line there (R10 counters: plain agent stores are write-through no-allocate -> every
// publish hit HBM and consumer polls re-fetched from HBM; WRITE_SIZE 237MB ~= 16 pubs
// x 64B x 4096 steps). Atomic publish keeps the exchange resident in the LLC.
__device__ __forceinline__ void exst(u64* p, u64 v) {
  (void)__hip_atomic_exchange(p, v, __ATOMIC_RELAXED, __HIP_MEMORY_SCOPE_AGENT);
}
__device__ __forceinline__ int pgld(const u32* p) {
  return (int)__hip_atomic_load(p, __ATOMIC_RELAXED, __HIP_MEMORY_SCOPE_AGENT);
}
__device__ __forceinline__ void pgst(u32* p, u32 v) {
  (void)__hip_atomic_exchange(p, v, __ATOMIC_RELAXED, __HIP_MEMORY_SCOPE_AGENT);
}

// fast activations: v_rcp + v_exp (no div sequences, no libm tanh)
__device__ __forceinline__ float frcp(float x) { return __builtin_amdgcn_rcpf(x); }
__device__ __forceinline__ float fsig(float x) { return frcp(1.f + __expf(-x)); }
__device__ __forceinline__ float ftnh(float x) { return 1.f - 2.f * frcp(1.f + __expf(2.f * x)); }

// ---------------- init: zero exchange slots (epoch0 == h_0 == 0) + progress flags ----------------
__global__ void init_sync_kernel(u64* ex, u32* prog) {
  const int tid = blockIdx.x * blockDim.x + threadIdx.x;
  if (tid < 2 * 2 * S_SLOT * HSZ) exst(&ex[tid], 0ull);
  if (tid < 2 * (NB0 + NB1)) pgst(&prog[tid], 0u);
}

// ---------------- fp32 GEMM with bias: P[t,r] = sum_k X[t,k]*W[r,k] + bi[r] + bh[r] ----------------
__global__ __launch_bounds__(256, 2)
void gemm_bias_kernel(const float* __restrict__ Xf, const float* __restrict__ Xb,
                      const float* __restrict__ Wf, const float* __restrict__ Wb,
                      const float* __restrict__ bif, const float* __restrict__ bhf,
                      const float* __restrict__ bib, const float* __restrict__ bhb,
                      float* __restrict__ Pf, float* __restrict__ Pb, int K)
{
  const int dir = blockIdx.z;
  const float* X  = dir ? Xb  : Xf;
  const float* W  = dir ? Wb  : Wf;
  const float* bi = dir ? bib : bif;
  const float* bh = dir ? bhb : bhf;
  float* P        = dir ? Pb  : Pf;

  const int m0 = blockIdx.x * 128;
  const int n0 = blockIdx.y * 128;
  const int tid = threadIdx.x;
  const int lr = tid >> 1;
  const int lk = (tid & 1) * 8;

  __shared__ float As[16*128];
  __shared__ float Bs[16*128];

  float acc[8][8];
  #pragma unroll
  for (int i = 0; i < 8; ++i)
    #pragma unroll
    for (int j = 0; j < 8; ++j) acc[i][j] = 0.f;

  for (int k0 = 0; k0 < K; k0 += 16) {
    const float4 a0 = *(const float4*)(X + (size_t)(m0+lr)*K + k0 + lk);
    const float4 a1 = *(const float4*)(X + (size_t)(m0+lr)*K + k0 + lk + 4);
    const float4 b0 = *(const float4*)(W + (size_t)(n0+lr)*K + k0 + lk);
    const float4 b1 = *(const float4*)(W + (size_t)(n0+lr)*K + k0 + lk + 4);
    __syncthreads();
    As[(lk+0)*128+lr]=a0.x; As[(lk+1)*128+lr]=a0.y; As[(lk+2)*128+lr]=a0.z; As[(lk+3)*128+lr]=a0.w;
    As[(lk+4)*128+lr]=a1.x; As[(lk+5)*128+lr]=a1.y; As[(lk+6)*128+lr]=a1.z; As[(lk+7)*128+lr]=a1.w;
    Bs[(lk+0)*128+lr]=b0.x; Bs[(lk+1)*128+lr]=b0.y; Bs[(lk+2)*128+lr]=b0.z; Bs[(lk+3)*128+lr]=b0.w;
    Bs[(lk+4)*128+lr]=b1.x; Bs[(lk+5)*128+lr]=b1.y; Bs[(lk+6)*128+lr]=b1.z; Bs[(lk+7)*128+lr]=b1.w;
    __syncthreads();
    #pragma unroll
    for (int kk = 0; kk < 16; ++kk) {
      const float4 A0 = *(const float4*)(As + kk*128 + (tid&15)*8);
      const float4 A1 = *(const float4*)(As + kk*128 + (tid&15)*8 + 4);
      const float4 B0 = *(const float4*)(Bs + kk*128 + (tid>>4)*8);
      const float4 B1 = *(const float4*)(Bs + kk*128 + (tid>>4)*8 + 4);
      const float av[8] = {A0.x,A0.y,A0.z,A0.w,A1.x,A1.y,A1.z,A1.w};
      const float bv[8] = {B0.x,B0.y,B0.z,B0.w,B1.x,B1.y,B1.z,B1.w};
      #pragma unroll
      for (int i = 0; i < 8; ++i)
        #pragma unroll
        for (int j = 0; j < 8; ++j) acc[i][j] += av[i]*bv[j];
    }
  }
  const int tm = m0 + (tid&15)*8;
  const int tn = n0 + (tid>>4)*8;
  #pragma unroll
  for (int i = 0; i < 8; ++i) {
    #pragma unroll
    for (int j = 0; j < 8; ++j) {
      const int n = tn + j;
      P[(size_t)(tm+i)*NGATE + n] = acc[i][j] + bi[n] + bh[n];
    }
  }
}

// ---------------- fused persistent recurrence: both layers, both directions, pipelined ----------------
// blocks [0,64): L0 (fwd 0..31, bwd 32..63)   [64,192): L1 (fwd 64..127, bwd 128..191)
// Exchange: u64 = (epoch<<32)|float_bits into slot epoch&(S_SLOT-1), agent scope.
// R4: 16-slot ring + lazy guard.  R5: in-wave gates, 1 barrier/step.  R10: 2x blocks, 64-col lanes.
// R13: publish via agent-scope atomic exchange -> line executes/allocates at the LLC instead
// of write-through to HBM (R10: WRITE_SIZE 237MB ~= per-publish HBM writes; polls re-fetched
// from HBM). Polls stay plain agent loads and now hit the LLC-resident line.
__global__ __launch_bounds__(512, 2)
void fused_recur_kernel(const float* __restrict__ Whh0_f, const float* __restrict__ Whh0_b,
                        const float* __restrict__ Wih1_f, const float* __restrict__ Whh1_f,
                        const float* __restrict__ bih1_f, const float* __restrict__ bhh1_f,
                        const float* __restrict__ Wih1_b, const float* __restrict__ Whh1_b,
                        const float* __restrict__ bih1_b, const float* __restrict__ bhh1_b,
                        const float* __restrict__ P_f, const float* __restrict__ P_b,
                        u64* ex0, u64* ex1, u32* prog0, u32* prog1,
                        float* __restrict__ out)
{
  const int bx  = blockIdx.x;
  const int tid = threadIdx.x;
  const int lane = tid & 63;
  const int wv   = tid >> 6;

  __shared__ __align__(16) float xh[2][16*CH0];   // double-buffered skewed 64-float chunks

  if (bx < 2*NB0) {
    // ---------------- layer 0 ----------------
    const int dir = (bx >= NB0) ? 1 : 0;
    const int b   = bx - dir*NB0;
    const float* Whh = dir ? Whh0_b : Whh0_f;
    const float* P   = dir ? P_b    : P_f;
    u64* exS   = ex0 + (size_t)dir*S_SLOT*HSZ;   // self exchange (also read by layer 1)
    u32* prS   = prog0 + dir*NB0;
    u32* prL1  = prog1 + dir*NB1;

    // lane = cc*8 + el*4 + g : 8 col-chunks of 64; 4 gates of an element adjacent
    const int g  = lane & 3;
    const int el = (lane >> 2) & 1;
    const int cc = lane >> 3;            // 0..7
    const int e  = wv*2 + el;            // 0..15 per block
    const int grow = g*HSZ + b*HB0 + e;  // global gate-row
    const bool red0 = (cc == 0);
    const bool pub  = red0 && (g == 0);

    float4 w[16];                        // 64 cols/lane
    {
      const float4* wp = (const float4*)(Whh + (size_t)grow*HSZ + cc*64);
      #pragma unroll
      for (int j = 0; j < 16; ++j) w[j] = wp[j];
    }

    float creg = 0.f;
    float pv = 0.f;
    if (red0) pv = P[(size_t)(dir ? (T_SEQ-1) : 0)*NGATE + grow];

    for (int t = 0; t < T_SEQ; ++t) {
      // slot-overwrite guard, every 8 steps (consumers: L0 peers + L1 blocks of this dir)
      if ((t & 7) == 0) {
        if (tid >= 64 && tid < 64+NB0)        { while (pgld(&prS[tid-64])  < t-4) {} }
        else if (tid >= 96 && tid < 96+NB1)   { while (pgld(&prL1[tid-96]) < t-4) {} }
      }
      // poll h_t (epoch t), stage to skewed LDS: chunk tid>>6, offset tid&63
      {
        const u64* sp = exS + (size_t)(t & (S_SLOT-1))*HSZ + tid;
        u64 v;
        do { v = exld(sp); } while ((u32)(v >> 32) != (u32)t);
        xh[t & 1][(tid>>6)*CH0 + (tid & 63)] = __uint_as_float((u32)v);
      }
      __syncthreads();
      if (tid == 0) pgst(&prS[b], (u32)(t+1));   // epoch-t reads complete
      // next-step P prefetch (one step of miss-hiding)
      float pvn = 0.f;
      if (red0 && t+1 < T_SEQ) pvn = P[(size_t)(dir ? (T_SEQ-2-t) : (t+1))*NGATE + grow];
      // matvec: 16 float4 from chunk cc (8 chunks x stride-68 floats: conflict-free broadcasts)
      const float4* h4 = (const float4*)(xh[t & 1] + cc*CH0);
      float a0=0.f, a1=0.f, a2=0.f, a3=0.f;
      #pragma unroll
      for (int j = 0; j < 16; j += 4) {
        const float4 h0 = h4[j], h1 = h4[j+1], h2 = h4[j+2], h3 = h4[j+3];
        a0 += w[j].x*h0.x   + w[j].y*h0.y   + w[j].z*h0.z   + w[j].w*h0.w;
        a1 += w[j+1].x*h1.x + w[j+1].y*h1.y + w[j+1].z*h1.z + w[j+1].w*h1.w;
        a2 += w[j+2].x*h2.x + w[j+2].y*h2.y + w[j+2].z*h2.z + w[j+2].w*h2.w;
        a3 += w[j+3].x*h3.x + w[j+3].y*h3.y + w[j+3].z*h3.z + w[j+3].w*h3.w;
      }
      float acc = (a0+a1)+(a2+a3);
      acc += __shfl_xor(acc, 8);           // reduce over cc (lane bits 3,4,5)
      acc += __shfl_xor(acc, 16);
      acc += __shfl_xor(acc, 32);
      const float val = acc + pv;          // full row value on cc==0 lanes
      pv = pvn;
      // parallel activation on the 4 gate lanes, then gather
      const float av = (g == 2) ? ftnh(val) : fsig(val);
      const float f1 = __shfl_xor(av, 1);
      const float f2 = __shfl_xor(av, 2);
      const float f3 = __shfl_xor(av, 3);
      if (pub) {
        // lane g=0: av=sig(i); f1=sig(f); f2=tanh(g); f3=sig(o)
        creg = f1*creg + av*f2;
        const float hnew = f3*ftnh(creg);
        const int hidx = b*HB0 + e;
        const u64 pkt = ((u64)(u32)(t+1) << 32) | (u64)__float_as_uint(hnew);
        exst(exS + (size_t)((t+1) & (S_SLOT-1))*HSZ + hidx, pkt);
        if (t == T_SEQ-1) {
          out[dir*HSZ + hidx]        = creg;   // cell_memories layer 0
          out[2048 + dir*HSZ + hidx] = hnew;   // hidden_states layer 0
        }
      }
    }
  } else {
    // ---------------- layer 1 ----------------
    const int r   = bx - 2*NB0;
    const int dir = (r >= NB1) ? 1 : 0;
    const int b   = r - dir*NB1;
    const float* Wih = dir ? Wih1_b : Wih1_f;
    const float* Whh = dir ? Whh1_b : Whh1_f;
    const float* bi  = dir ? bih1_b : bih1_f;
    const float* bh  = dir ? bhh1_b : bhh1_f;
    u64* exX = ex0 + (size_t)dir*S_SLOT*HSZ;     // x source = layer-0 outputs
    u64* exS = ex1 + (size_t)dir*S_SLOT*HSZ;     // self h exchange
    u32* prS = prog1 + dir*NB1;

    // lane = cc*4 + g : 16 col-chunks of 64 (0-7: Wih/x, 8-15: Whh/h); wave = element
    const int g  = lane & 3;
    const int cc = lane >> 2;            // 0..15
    const int e  = wv;                   // 0..7 per block
    const int grow = g*HSZ + b*HB1 + e;
    const bool red0 = (cc == 0);
    const bool pub  = red0 && (g == 0);

    float4 w[16];                        // 64 cols/lane
    {
      const float* wsrc = (cc < 8) ? (Wih + (size_t)grow*HSZ + cc*64)
                                   : (Whh + (size_t)grow*HSZ + (cc-8)*64);
      const float4* wp = (const float4*)wsrc;
      #pragma unroll
      for (int j = 0; j < 16; ++j) w[j] = wp[j];
    }
    float brow = 0.f;
    if (red0) brow = bi[grow] + bh[grow];

    float creg = 0.f;
    u64 xpf = exld(exX + (size_t)(1 & (S_SLOT-1))*HSZ + tid);   // prefetch x epoch 1

    for (int t = 0; t < T_SEQ; ++t) {
      // slot-overwrite guard, every 8 steps (consumers of ex1: L1 peers of this dir)
      if ((t & 7) == 0 && tid >= 64 && tid < 64+NB1) { while (pgld(&prS[tid-64]) < t-4) {} }
      // poll x_t (epoch t+1; usually satisfied by prefetch) and own h_t (epoch t)
      {
        const u64* px = exX + (size_t)((t+1) & (S_SLOT-1))*HSZ + tid;
        const u64* ph = exS + (size_t)(t & (S_SLOT-1))*HSZ + tid;
        u64 vx = xpf; bool okx = ((u32)(vx >> 32) == (u32)(t+1));
        float hv = 0.f; bool okh = false;
        do {
          if (!okx) { u64 v = exld(px); if ((u32)(v >> 32) == (u32)(t+1)) { vx = v; okx = true; } }
          if (!okh) { u64 v = exld(ph); if ((u32)(v >> 32) == (u32)t)     { hv = __uint_as_float((u32)v); okh = true; } }
        } while (!(okx && okh));
        xh[t & 1][(tid>>6)*CH0 + (tid & 63)]       = __uint_as_float((u32)vx);   // chunks 0..7 (x)
        xh[t & 1][(8 + (tid>>6))*CH0 + (tid & 63)] = hv;                         // chunks 8..15 (h)
      }
      __syncthreads();
      if (tid == 0) pgst(&prS[b], (u32)(t+1));
      xpf = exld(exX + (size_t)((t+2) & (S_SLOT-1))*HSZ + tid);   // prefetch next x (epoch-tagged)
      // matvec: 16 float4 from chunk cc
      const float4* v4 = (const float4*)(xh[t & 1] + cc*CH0);
      float a0=0.f, a1=0.f, a2=0.f, a3=0.f;
      #pragma unroll
      for (int j = 0; j < 16; j += 4) {
        const float4 h0 = v4[j], h1 = v4[j+1], h2 = v4[j+2], h3 = v4[j+3];
        a0 += w[j].x*h0.x   + w[j].y*h0.y   + w[j].z*h0.z   + w[j].w*h0.w;
        a1 += w[j+1].x*h1.x + w[j+1].y*h1.y + w[j+1].z*h1.z + w[j+1].w*h1.w;
        a2 += w[j+2].x*h2.x + w[j+2].y*h2.y + w[j+2].z*h2.z + w[j+2].w*h2.w;
        a3 += w[j+3].x*h3.x + w[j+3].y*h3.y + w[j+3].z*h3.z + w[j+3].w*h3.w;
      }
      float acc = (a0+a1)+(a2+a3);
      acc += __shfl_xor(acc, 4);           // reduce over cc (lane bits 2,3,4,5)
      acc += __shfl_xor(acc, 8);
      acc += __shfl_xor(acc, 16);
      acc += __shfl_xor(acc, 32);
      const float val = acc + brow;
      const float av = (g == 2) ? ftnh(val) : fsig(val);
      const float f1 = __shfl_xor(av, 1);
      const float f2 = __shfl_xor(av, 2);
      const float f3 = __shfl_xor(av, 3);
      if (pub) {
        creg = f1*creg + av*f2;
        const float hnew = f3*ftnh(creg);
        const int hidx = b*HB1 + e;
        const u64 pkt = ((u64)(u32)(t+1) << 32) | (u64)__float_as_uint(hnew);
        exst(exS + (size_t)((t+1) & (S_SLOT-1))*HSZ + hidx, pkt);
        const int trow = dir ? (T_SEQ-1-t) : t;
        out[4096 + (size_t)trow*1024 + dir*HSZ + hidx] = hnew;   // top-layer outputs
        if (t == T_SEQ-1) {
          out[1024 + dir*HSZ + hidx]        = creg;   // cell_memories layer 1
          out[2048 + 1024 + dir*HSZ + hidx] = hnew;   // hidden_states layer 1
        }
      }
    }
  }
}

// ---------------- launch ----------------
extern "C" void kernel_launch(void* const* d_in, const int* in_sizes, int n_in,
                              void* d_out, int out_size, void* d_ws, size_t ws_size,
                              hipStream_t stream)
{
  const float* emb   = (const float*)d_in[0];
  const float* fWih0 = (const float*)d_in[1];
  const float* fWhh0 = (const float*)d_in[2];
  const float* fbih0 = (const float*)d_in[3];
  const float* fbhh0 = (const float*)d_in[4];
  const float* fWih1 = (const float*)d_in[5];
  const float* fWhh1 = (const float*)d_in[6];
  const float* fbih1 = (const float*)d_in[7];
  const float* fbhh1 = (const float*)d_in[8];
  const float* bWih0 = (const float*)d_in[9];
  const float* bWhh0 = (const float*)d_in[10];
  const float* bbih0 = (const float*)d_in[11];
  const float* bbhh0 = (const float*)d_in[12];
  const float* bWih1 = (const float*)d_in[13];
  const float* bWhh1 = (const float*)d_in[14];
  const float* bbih1 = (const float*)d_in[15];
  const float* bbhh1 = (const float*)d_in[16];
  float* out = (float*)d_out;

  // workspace: P[2][4096][2048] fp32 (67 MB), ex0/ex1 [2][S_SLOT][512] u64 each, progress flags
  float* P_f = (float*)d_ws;
  float* P_b = P_f + (size_t)T_SEQ*NGATE;
  u64*   ex0 = (u64*)(P_b + (size_t)T_SEQ*NGATE);
  u64*   ex1 = ex0 + 2*S_SLOT*HSZ;
  u32*   prog0 = (u32*)(ex1 + 2*S_SLOT*HSZ);
  u32*   prog1 = prog0 + 2*NB0;

  init_sync_kernel<<<32, 1024, 0, stream>>>(ex0, prog0);

  // layer-0 input projections for both directions (bwd reads P reversed in time)
  gemm_bias_kernel<<<dim3(32,16,2), 256, 0, stream>>>(
      emb, emb, fWih0, bWih0, fbih0, fbhh0, bbih0, bbhh0, P_f, P_b, DIN);

  // fused pipelined recurrence: L0 fwd/bwd + L1 fwd/bwd in one persistent launch
  fused_recur_kernel<<<2*NB0 + 2*NB1, 512, 0, stream>>>(
      fWhh0, bWhh0,
      fWih1, fWhh1, fbih1, fbhh1,
      bWih1, bWhh1, bbih1, bbhh1,
      P_f, P_b, ex0, ex1, prog0, prog1, out);
}